// Round 8
// baseline (411.030 us; speedup 1.0000x reference)
//
#include <hip/hip_runtime.h>
#include <hip/hip_bf16.h>
#include <math.h>

typedef __hip_bfloat16 bf16;
typedef __attribute__((ext_vector_type(8))) short bf16x8;
typedef __attribute__((ext_vector_type(4))) float f32x4;

// ---------------- dtype-flexible accessors ----------------
__device__ __forceinline__ float loadf(const void* p, size_t i, bool f32m) {
    return f32m ? ((const float*)p)[i]
                : __bfloat162float(((const bf16*)p)[i]);
}
__device__ __forceinline__ void storef(void* p, size_t i, float v, bool f32m) {
    if (f32m) ((float*)p)[i] = v;
    else      ((bf16*)p)[i] = __float2bfloat16(v);
}
// row 0 = src, row 1 = dst; e64 => int64 buffer, read low word
__device__ __forceinline__ int ldidx(const int* w, size_t e, bool e64, size_t E, int row) {
    return e64 ? w[2 * (row * E + e)] : w[row * E + e];
}

// f32 <-> bf16-bits helpers (RNE), branch-free
__device__ __forceinline__ unsigned short f2bf(float f) {
    unsigned u = __float_as_uint(f);
    unsigned r = (u + 0x7FFFu + ((u >> 16) & 1u)) >> 16;
    return (unsigned short)r;
}
__device__ __forceinline__ float bf2f(unsigned short h) {
    return __uint_as_float(((unsigned)h) << 16);
}

// ---------------- dtype detection (one wave) ----------------
__global__ void k_detect(const void* x, const int* ei, float* flags) {
    int lane = threadIdx.x;
    const unsigned short* hx = (const unsigned short*)x;
    unsigned short u = hx[2 * lane];
    int ex = (u >> 7) & 0xFF;
    bool tame = (ex >= 117 && ex <= 136);
    unsigned long long mt = __ballot(tame);
    unsigned long long mz = __ballot(ei[2 * lane + 1] != 0);
    if (lane == 0) {
        flags[0] = (__popcll(mt) >= 48) ? 0.0f : 1.0f;  // 1 => f32 inputs
        flags[1] = (mz == 0ULL) ? 1.0f : 0.0f;          // 1 => int64 edge_index
    }
}

// ---------------- direct CSR build: deg atomics -> 2-level scan -> fill ----------------

#define SCB_EPT 16   // edges per thread (4096 per block)

__global__ void k_zero_deg(int* __restrict__ deg, int n) {
    int i = blockIdx.x * 256 + threadIdx.x;
    if (i < n) deg[i] = 0;
}

__global__ __launch_bounds__(256) void k_deg(const int* __restrict__ ei,
                                             const float* __restrict__ flags,
                                             int* __restrict__ deg, int E) {
    bool e64 = flags[1] > 0.5f;
    int tid = threadIdx.x;
    int base = blockIdx.x * 256 * SCB_EPT;
#pragma unroll
    for (int j = 0; j < SCB_EPT; ++j) {
        int e = base + j * 256 + tid;
        if (e < E) atomicAdd(&deg[ldidx(ei, e, e64, E, 1)], 1);
    }
}

// per-256-chunk exclusive prefix (lpre) + chunk total (ctot)
__global__ __launch_bounds__(256) void k_scanA(const int* __restrict__ deg,
                                               int* __restrict__ lpre,
                                               int* __restrict__ ctot, int n) {
    __shared__ int sh[256];
    int b = blockIdx.x, tid = threadIdx.x;
    int i = b * 256 + tid;
    int v = (i < n) ? deg[i] : 0;
    sh[tid] = v;
    __syncthreads();
    for (int off = 1; off < 256; off <<= 1) {
        int t = (tid >= off) ? sh[tid - off] : 0;
        __syncthreads();
        sh[tid] += t;
        __syncthreads();
    }
    if (i < n) lpre[i] = sh[tid] - v;     // exclusive within chunk
    if (tid == 255) ctot[b] = sh[255];
}

// single block: exclusive scan of the <=512 chunk totals
__global__ __launch_bounds__(512) void k_scanB(const int* __restrict__ ctot,
                                               int* __restrict__ cbase, int NCH) {
    __shared__ int sh[512];
    int tid = threadIdx.x;
    int v = (tid < NCH) ? ctot[tid] : 0;
    sh[tid] = v;
    __syncthreads();
    for (int off = 1; off < 512; off <<= 1) {
        int t = (tid >= off) ? sh[tid - off] : 0;
        __syncthreads();
        sh[tid] += t;
        __syncthreads();
    }
    if (tid < NCH) cbase[tid] = sh[tid] - v;
}

// combine: rowptr/cur/dinv
__global__ __launch_bounds__(256) void k_scanC(const int* __restrict__ deg,
                                               const int* __restrict__ lpre,
                                               const int* __restrict__ cbase,
                                               int* __restrict__ rowptr,
                                               float* __restrict__ dinv,
                                               int* __restrict__ cur, int n, int E) {
    int i = blockIdx.x * 256 + threadIdx.x;
    if (i < n) {
        int rp = cbase[i >> 8] + lpre[i];
        rowptr[i] = rp;
        cur[i] = rp;
        dinv[i] = rsqrtf((float)(deg[i] + 1));
    }
    if (i == 0) rowptr[n] = E;
}

__global__ __launch_bounds__(256) void k_fill(const int* __restrict__ ei,
                                              const float* __restrict__ flags,
                                              int* __restrict__ cur,
                                              int* __restrict__ srcs, int E) {
    bool e64 = flags[1] > 0.5f;
    int tid = threadIdx.x;
    int base = blockIdx.x * 256 * SCB_EPT;
#pragma unroll
    for (int j = 0; j < SCB_EPT; ++j) {
        int e = base + j * 256 + tid;
        if (e < E) {
            int s = ldidx(ei, e, e64, E, 0);
            int d = ldidx(ei, e, e64, E, 1);
            int pos = atomicAdd(&cur[d], 1);
            srcs[pos] = s;
        }
    }
}

// ---------------- MFMA dense transform (both modes): A = (X @ W)*rowscale ----------------
// f32 data path uses split-bf16 (hi+lo) with 3 MFMAs per product tile:
//   x*w ~= xh*wh + xh*wl + xl*wh      (drops xl*wl, ~2^-16 relative)
// bf16 data degenerates to lo==0. 4 waves/block, 64 rows x 64 cols per block.
template <int K, bool XALWAYSF32>
__global__ __launch_bounds__(256) void k_gconv_mfma(const void* __restrict__ Xa,
                                                    const void* __restrict__ Xb,
                                                    const void* __restrict__ W,
                                                    const float* __restrict__ flags,
                                                    const float* __restrict__ rowscale,
                                                    float* __restrict__ out, int n) {
    constexpr int KP = K + 8;
    __shared__ __align__(16) unsigned short wh[64 * KP];
    __shared__ __align__(16) unsigned short wlo[64 * KP];
    bool f32m = flags[0] > 0.5f;
    const void* X = f32m ? Xa : Xb;
    bool xf32 = XALWAYSF32 || f32m;
    int tid = threadIdx.x;

    // stage W^T split into hi/lo bf16 bits
    if (f32m) {
        for (int i = tid * 4; i < K * 64; i += 1024) {
            int k = i >> 6, c = i & 63;
            float4 v = *(const float4*)((const float*)W + i);
            float vv[4] = {v.x, v.y, v.z, v.w};
#pragma unroll
            for (int q = 0; q < 4; ++q) {
                unsigned short h = f2bf(vv[q]);
                unsigned short l = f2bf(vv[q] - bf2f(h));
                wh [(c + q) * KP + k] = h;
                wlo[(c + q) * KP + k] = l;
            }
        }
    } else {
        for (int i = tid; i < K * 64; i += 256) {
            int k = i >> 6, c = i & 63;
            wh [c * KP + k] = ((const unsigned short*)W)[i];
            wlo[c * KP + k] = 0;
        }
    }
    __syncthreads();

    int lane = tid & 63, wv = tid >> 6;
    int r0 = blockIdx.x * 64 + wv * 16;
    int mrow = lane & 15, kgrp = lane >> 4;
    int row = r0 + mrow;
    bool rok = (row < n);

    f32x4 acc[4];
#pragma unroll
    for (int ct = 0; ct < 4; ++ct) acc[ct] = (f32x4){0.0f, 0.0f, 0.0f, 0.0f};

    const float*          xrf = (const float*)X          + (size_t)(rok ? row : 0) * K;
    const unsigned short* xrb = (const unsigned short*)X + (size_t)(rok ? row : 0) * K;

#pragma unroll
    for (int ks = 0; ks < K / 32; ++ks) {
        int kb = ks * 32 + kgrp * 8;
        bf16x8 ahi = {0, 0, 0, 0, 0, 0, 0, 0};
        bf16x8 alo = {0, 0, 0, 0, 0, 0, 0, 0};
        if (rok) {
            if (xf32) {
                float4 v0 = *(const float4*)(xrf + kb);
                float4 v1 = *(const float4*)(xrf + kb + 4);
                float fv[8] = {v0.x, v0.y, v0.z, v0.w, v1.x, v1.y, v1.z, v1.w};
#pragma unroll
                for (int j = 0; j < 8; ++j) {
                    unsigned short h = f2bf(fv[j]);
                    ahi[j] = (short)h;
                    alo[j] = (short)f2bf(fv[j] - bf2f(h));
                }
            } else {
                ahi = *(const bf16x8*)(xrb + kb);   // alo stays 0
            }
        }
#pragma unroll
        for (int ct = 0; ct < 4; ++ct) {
            int c = ct * 16 + mrow;
            bf16x8 bhi = *(const bf16x8*)&wh [c * KP + kb];
            bf16x8 blo = *(const bf16x8*)&wlo[c * KP + kb];
            acc[ct] = __builtin_amdgcn_mfma_f32_16x16x32_bf16(ahi, bhi, acc[ct], 0, 0, 0);
            acc[ct] = __builtin_amdgcn_mfma_f32_16x16x32_bf16(ahi, blo, acc[ct], 0, 0, 0);
            acc[ct] = __builtin_amdgcn_mfma_f32_16x16x32_bf16(alo, bhi, acc[ct], 0, 0, 0);
        }
    }

    // C/D: col = ct*16 + (lane&15), row(within tile) = kgrp*4 + reg
    float sc[4];
    int obase = r0 + kgrp * 4;
#pragma unroll
    for (int r = 0; r < 4; ++r)
        sc[r] = (obase + r < n) ? rowscale[obase + r] : 0.0f;
#pragma unroll
    for (int ct = 0; ct < 4; ++ct) {
#pragma unroll
        for (int r = 0; r < 4; ++r) {
            int orow = obase + r;
            if (orow < n)
                out[(size_t)orow * 64 + ct * 16 + mrow] = acc[ct][r] * sc[r];
        }
    }
}

// ---------------- fused aggregation: 1 node per 16-lane group (4/wave) ----------------
// t = f32 A_scaled (rows pre-multiplied by dinv[src]); each lane owns 4 fixed
// columns -> in-register accumulation, NO cross-lane reduction. 4 independent
// gather chains per wave, 4-deep unrolled -> up to 16 rows (256B each) in flight.
template <int EP>
__global__ __launch_bounds__(256) void k_agg(const float* __restrict__ t,
                                             const float* __restrict__ dinv,
                                             const int* __restrict__ rowptr,
                                             const int* __restrict__ srcs,
                                             const void* __restrict__ bias,
                                             const float* __restrict__ flags,
                                             void* __restrict__ d_out, size_t emb_base,
                                             float* __restrict__ B_ws, int n) {
    bool f32m = flags[0] > 0.5f;
    int wvid = (blockIdx.x * 256 + threadIdx.x) >> 6;   // global wave id
    int lane = threadIdx.x & 63;
    int grp = lane >> 4;      // group = node slot
    int sub = lane & 15;      // column group: cols sub*4 .. sub*4+3
    int v = wvid * 4 + grp;
    if (v >= n) return;

    float dv = dinv[v];
    int e0 = rowptr[v], e1 = rowptr[v + 1];
    int deg = e1 - e0;

    // self row (item outside the neighbor loop)
    float4 acc = *(const float4*)(t + ((size_t)v << 6) + sub * 4);

    for (int base = 0; base < deg; base += 16) {
        int idx = base + sub;
        int sid = (idx < deg) ? srcs[e0 + idx] : -1;   // 16 ids per group, coalesced
        int cnt = deg - base; if (cnt > 16) cnt = 16;
        for (int j = 0; j < cnt; j += 4) {
            int gb = grp * 16 + j;
            int s0 = __shfl(sid, gb + 0, 64);
            int s1 = __shfl(sid, gb + 1, 64);
            int s2 = __shfl(sid, gb + 2, 64);
            int s3 = __shfl(sid, gb + 3, 64);
            float4 r0 = {0, 0, 0, 0}, r1 = {0, 0, 0, 0}, r2 = {0, 0, 0, 0}, r3 = {0, 0, 0, 0};
            if (s0 >= 0) r0 = *(const float4*)(t + ((size_t)s0 << 6) + sub * 4);
            if (s1 >= 0) r1 = *(const float4*)(t + ((size_t)s1 << 6) + sub * 4);
            if (s2 >= 0) r2 = *(const float4*)(t + ((size_t)s2 << 6) + sub * 4);
            if (s3 >= 0) r3 = *(const float4*)(t + ((size_t)s3 << 6) + sub * 4);
            acc.x += (r0.x + r1.x) + (r2.x + r3.x);
            acc.y += (r0.y + r1.y) + (r2.y + r3.y);
            acc.z += (r0.z + r1.z) + (r2.z + r3.z);
            acc.w += (r0.w + r1.w) + (r2.w + r3.w);
        }
    }

    // bias for this lane's column group
    float4 bias4;
    if (f32m) {
        bias4 = ((const float4*)bias)[sub];
    } else {
        const bf16* bp = (const bf16*)bias + sub * 4;
        bias4.x = __bfloat162float(bp[0]); bias4.y = __bfloat162float(bp[1]);
        bias4.z = __bfloat162float(bp[2]); bias4.w = __bfloat162float(bp[3]);
    }

    float4 o;
    o.x = acc.x * dv + bias4.x;
    o.y = acc.y * dv + bias4.y;
    o.z = acc.z * dv + bias4.z;
    o.w = acc.w * dv + bias4.w;
    if (EP == 0) {
        o.x = fmaxf(o.x, 0.0f); o.y = fmaxf(o.y, 0.0f);
        o.z = fmaxf(o.z, 0.0f); o.w = fmaxf(o.w, 0.0f);
    }
    size_t ob = ((size_t)v << 6) + sub * 4;
    if (f32m) {
        *(float4*)((float*)d_out + emb_base + ob) = o;   // 16 lanes -> 256B row
    } else {
        *(float4*)&B_ws[ob] = o;
        if (EP == 1) {
            __hip_bfloat162 h0, h1;
            h0.x = __float2bfloat16(o.x); h0.y = __float2bfloat16(o.y);
            h1.x = __float2bfloat16(o.z); h1.y = __float2bfloat16(o.w);
            __hip_bfloat162* p = (__hip_bfloat162*)((bf16*)d_out + emb_base + ob);
            p[0] = h0; p[1] = h1;
        }
    }
}

// ---------------- classifier: one thread per node, logits in registers ----------------

__device__ __forceinline__ void store_row40(void* out, size_t base, const float* a, bool f32m) {
    if (f32m) {
        float4* p = (float4*)((float*)out + base);
#pragma unroll
        for (int q = 0; q < 10; ++q) {
            float4 st = {a[q * 4 + 0], a[q * 4 + 1], a[q * 4 + 2], a[q * 4 + 3]};
            p[q] = st;
        }
    } else {
        __hip_bfloat162* p = (__hip_bfloat162*)((bf16*)out + base);
#pragma unroll
        for (int i = 0; i < 20; ++i) {
            __hip_bfloat162 h;
            h.x = __float2bfloat16(a[2 * i]);
            h.y = __float2bfloat16(a[2 * i + 1]);
            p[i] = h;
        }
    }
}

__global__ __launch_bounds__(256) void k_classifier(const float* __restrict__ flags,
                                                    const void* __restrict__ Wc,
                                                    const void* __restrict__ bc,
                                                    void* __restrict__ out,
                                                    size_t emb_base, size_t soft_base,
                                                    size_t hard_base,
                                                    const float* __restrict__ B_ws,
                                                    int n) {
    __shared__ __align__(16) float wcs[64 * 40];
    __shared__ __align__(16) float bcs[40];
    bool f32m = flags[0] > 0.5f;
    const float* emb = f32m ? ((const float*)out + emb_base) : B_ws;
    int tid = threadIdx.x;

    if (f32m) {
        for (int i = tid * 4; i < 64 * 40; i += 1024)
            *(float4*)&wcs[i] = *(const float4*)((const float*)Wc + i);
    } else {
        for (int i = tid; i < 64 * 40; i += 256)
            wcs[i] = __bfloat162float(((const bf16*)Wc)[i]);
    }
    if (tid < 40) bcs[tid] = loadf(bc, tid, f32m);
    __syncthreads();

    int node = blockIdx.x * 256 + tid;
    if (node >= n) return;

    float acc[40];
#pragma unroll
    for (int q = 0; q < 10; ++q) {
        float4 b4 = *(const float4*)&bcs[q * 4];
        acc[q * 4 + 0] = b4.x; acc[q * 4 + 1] = b4.y;
        acc[q * 4 + 2] = b4.z; acc[q * 4 + 3] = b4.w;
    }

    const float4* erow = (const float4*)(emb + (size_t)node * 64);
#pragma unroll 2
    for (int j = 0; j < 16; ++j) {
        float4 e4 = erow[j];
        float ev[4] = {e4.x, e4.y, e4.z, e4.w};
#pragma unroll
        for (int kk = 0; kk < 4; ++kk) {
            float e = ev[kk];
            const float4* wr = (const float4*)&wcs[(j * 4 + kk) * 40];
#pragma unroll
            for (int q = 0; q < 10; ++q) {
                float4 w = wr[q];                       // wave-uniform LDS broadcast
                acc[q * 4 + 0] = fmaf(e, w.x, acc[q * 4 + 0]);
                acc[q * 4 + 1] = fmaf(e, w.y, acc[q * 4 + 1]);
                acc[q * 4 + 2] = fmaf(e, w.z, acc[q * 4 + 2]);
                acc[q * 4 + 3] = fmaf(e, w.w, acc[q * 4 + 3]);
            }
        }
    }

    // logits
    store_row40(out, (size_t)node * 40, acc, f32m);

    // max (tree)
    float m0 = acc[0], m1 = acc[1], m2 = acc[2], m3 = acc[3];
#pragma unroll
    for (int q = 1; q < 10; ++q) {
        m0 = fmaxf(m0, acc[q * 4 + 0]); m1 = fmaxf(m1, acc[q * 4 + 1]);
        m2 = fmaxf(m2, acc[q * 4 + 2]); m3 = fmaxf(m3, acc[q * 4 + 3]);
    }
    float m = fmaxf(fmaxf(m0, m1), fmaxf(m2, m3));

    // argmax: first index equal to max (matches jnp.argmax first-occurrence)
    int bi = 63;
#pragma unroll
    for (int c = 0; c < 40; ++c)
        if (acc[c] == m && c < bi) bi = c;

    // exp + sum
    float s = 0.0f;
#pragma unroll
    for (int c = 0; c < 40; ++c) {
        float e = expf(acc[c] - m);
        acc[c] = e;
        s += e;
    }
    float rs = 1.0f / s;
#pragma unroll
    for (int c = 0; c < 40; ++c) acc[c] *= rs;

    store_row40(out, soft_base + (size_t)node * 40, acc, f32m);
    storef(out, hard_base + node, (float)bi, f32m);
}

extern "C" void kernel_launch(void* const* d_in, const int* in_sizes, int n_in,
                              void* d_out, int out_size, void* d_ws, size_t ws_size,
                              hipStream_t stream) {
    const void* x  = d_in[0];
    const int*  ei = (const int*)d_in[1];
    const void* W1 = d_in[2];
    const void* b1 = d_in[3];
    const void* W2 = d_in[4];
    const void* b2 = d_in[5];
    const void* Wc = d_in[6];
    const void* bc = d_in[7];

    const int n = in_sizes[0] / 128;   // 100000
    const int E = in_sizes[1] / 2;     // 1200000
    const int NCH = (n + 255) / 256;   // 391 chunks (<= 512)

    float* ws    = (float*)d_ws;
    const size_t npad = (((size_t)n + 1023) / 1024) * 1024;
    const size_t Epad = (((size_t)E + 255) / 256) * 256;
    float* flags  = ws;                         // 256
    int*   rowptr = (int*)(ws + 2048);          // npad (n+1 used)
    float* dinv   = (float*)(rowptr + npad);    // npad
    int*   srcs   = (int*)(dinv + npad);        // Epad
    float* A      = (float*)(srcs + Epad);      // n*64 f32 (scaled gemm outputs)
    float* B_ws   = A + (size_t)n * 64;         // n*64 f32 (only if !f32m)

    // CSR-build scratch aliases B_ws (dead until k_agg<0> writes it)
    int*   deg    = (int*)B_ws;                 // npad
    int*   lpre   = deg + npad;                 // npad
    int*   ctot   = lpre + npad;                // 512
    int*   cbase  = ctot + 512;                 // 512
    int*   cur    = cbase + 512;                // npad

    const size_t emb_base  = (size_t)n * 40;
    const size_t soft_base = (size_t)n * 104;
    const size_t hard_base = (size_t)n * 144;
    float* h1_f32m = (float*)d_out + emb_base;  // h1 scratch in emb region (f32m)

    const int gE  = (E + 256 * SCB_EPT - 1) / (256 * SCB_EPT);  // edge-pass blocks
    const int gN  = (n + 255) / 256;
    const int gG  = (n + 63) / 64;
    const int gW  = (n + 15) / 16;              // 4 nodes/wave, 4 waves/block
    const int gC  = (n + 255) / 256;

    k_detect<<<1, 64, 0, stream>>>(x, ei, flags);

    // direct CSR build: deg atomics -> 2-level node scan -> fill
    k_zero_deg<<<gN, 256, 0, stream>>>(deg, n);
    k_deg<<<gE, 256, 0, stream>>>(ei, flags, deg, E);
    k_scanA<<<NCH, 256, 0, stream>>>(deg, lpre, ctot, n);
    k_scanB<<<1, 512, 0, stream>>>(ctot, cbase, NCH);
    k_scanC<<<gN, 256, 0, stream>>>(deg, lpre, cbase, rowptr, dinv, cur, n, E);
    k_fill<<<gE, 256, 0, stream>>>(ei, flags, cur, srcs, E);

    // conv1: A = (x @ W1)*dinv  — split-bf16 MFMA (f32 mode) / plain MFMA (bf16 mode)
    k_gconv_mfma<128, false><<<gG, 256, 0, stream>>>(x, x, W1, flags, dinv, A, n);
    k_agg<0><<<gW, 256, 0, stream>>>(A, dinv, rowptr, srcs, b1, flags,
                                     d_out, emb_base, B_ws, n);

    // conv2: A = (h1 @ W2)*dinv ; h1 is f32 in both modes
    k_gconv_mfma<64, true><<<gG, 256, 0, stream>>>(h1_f32m, B_ws, W2, flags, dinv, A, n);
    k_agg<1><<<gW, 256, 0, stream>>>(A, dinv, rowptr, srcs, b2, flags,
                                     d_out, emb_base, B_ws, n);

    // classifier + softmax + argmax
    k_classifier<<<gC, 256, 0, stream>>>(flags, Wc, bc, d_out,
                                         emb_base, soft_base, hard_base, B_ws, n);
}

// Round 9
// 313.269 us; speedup vs baseline: 1.3121x; 1.3121x over previous
//
#include <hip/hip_runtime.h>
#include <hip/hip_bf16.h>
#include <math.h>

typedef __hip_bfloat16 bf16;
typedef __attribute__((ext_vector_type(8))) short bf16x8;
typedef __attribute__((ext_vector_type(4))) float f32x4;

// ---------------- dtype-flexible accessors ----------------
__device__ __forceinline__ float loadf(const void* p, size_t i, bool f32m) {
    return f32m ? ((const float*)p)[i]
                : __bfloat162float(((const bf16*)p)[i]);
}
__device__ __forceinline__ void storef(void* p, size_t i, float v, bool f32m) {
    if (f32m) ((float*)p)[i] = v;
    else      ((bf16*)p)[i] = __float2bfloat16(v);
}
// row 0 = src, row 1 = dst; e64 => int64 buffer, read low word
__device__ __forceinline__ int ldidx(const int* w, size_t e, bool e64, size_t E, int row) {
    return e64 ? w[2 * (row * E + e)] : w[row * E + e];
}

// f32 <-> bf16-bits helpers (RNE), branch-free
__device__ __forceinline__ unsigned short f2bf(float f) {
    unsigned u = __float_as_uint(f);
    unsigned r = (u + 0x7FFFu + ((u >> 16) & 1u)) >> 16;
    return (unsigned short)r;
}
__device__ __forceinline__ float bf2f(unsigned short h) {
    return __uint_as_float(((unsigned)h) << 16);
}

// ---------------- dtype detection (one wave) ----------------
__global__ void k_detect(const void* x, const int* ei, float* flags) {
    int lane = threadIdx.x;
    const unsigned short* hx = (const unsigned short*)x;
    unsigned short u = hx[2 * lane];
    int ex = (u >> 7) & 0xFF;
    bool tame = (ex >= 117 && ex <= 136);
    unsigned long long mt = __ballot(tame);
    unsigned long long mz = __ballot(ei[2 * lane + 1] != 0);
    if (lane == 0) {
        flags[0] = (__popcll(mt) >= 48) ? 0.0f : 1.0f;  // 1 => f32 inputs
        flags[1] = (mz == 0ULL) ? 1.0f : 0.0f;          // 1 => int64 edge_index
    }
}

// ---------------- CSR build: 2-level counting sort ----------------
// bucket = dst >> 8 (256 nodes per bucket), NB = ceil(n/256) <= 512
// recs packed: (src << 8) | (dst & 255)  — src < 2^17, bucket known from range.

__global__ void k_zero_small(int* __restrict__ p, int m) {
    int i = blockIdx.x * 256 + threadIdx.x;
    if (i < m) p[i] = 0;
}

#define SCB_EPT 16   // edges per thread in hist/scatter (4096 per block)

__global__ __launch_bounds__(256) void k_bucket_hist(const int* __restrict__ ei,
                                                     const float* __restrict__ flags,
                                                     int* __restrict__ bcnt, int E, int NB) {
    __shared__ int lcnt[512];
    bool e64 = flags[1] > 0.5f;
    int tid = threadIdx.x;
    for (int i = tid; i < NB; i += 256) lcnt[i] = 0;
    __syncthreads();
    int base = blockIdx.x * 256 * SCB_EPT;
#pragma unroll
    for (int j = 0; j < SCB_EPT; ++j) {
        int e = base + j * 256 + tid;
        if (e < E) atomicAdd(&lcnt[ldidx(ei, e, e64, E, 1) >> 8], 1);
    }
    __syncthreads();
    for (int i = tid; i < NB; i += 256) {
        int c = lcnt[i];
        if (c) atomicAdd(&bcnt[i], c);
    }
}

// single block of 512: scan bcnt -> bbase (exclusive, NB+1), bcur copy
__global__ __launch_bounds__(512) void k_scan_buckets(const int* __restrict__ bcnt,
                                                      int* __restrict__ bbase,
                                                      int* __restrict__ bcur, int NB) {
    __shared__ int sh[512];
    int tid = threadIdx.x;
    int v = (tid < NB) ? bcnt[tid] : 0;
    sh[tid] = v;
    __syncthreads();
    for (int off = 1; off < 512; off <<= 1) {
        int t = (tid >= off) ? sh[tid - off] : 0;
        __syncthreads();
        sh[tid] += t;
        __syncthreads();
    }
    if (tid < NB) {
        int ex = sh[tid] - v;
        bbase[tid] = ex;
        bcur[tid] = ex;
    }
    if (tid == 0) bbase[NB] = sh[511];
}

// scatter packed (src,dst&255) records into bucket regions; per-block LDS rank ->
// consecutive positions per (block,bucket) -> near-sequential writes
__global__ __launch_bounds__(256) void k_bucket_scatter(const int* __restrict__ ei,
                                                        const float* __restrict__ flags,
                                                        int* __restrict__ bcur,
                                                        unsigned* __restrict__ recs,
                                                        int E, int NB) {
    __shared__ int lcnt[512], lrank[512], lbase[512];
    bool e64 = flags[1] > 0.5f;
    int tid = threadIdx.x;
    for (int i = tid; i < NB; i += 256) { lcnt[i] = 0; lrank[i] = 0; }
    __syncthreads();
    int base = blockIdx.x * 256 * SCB_EPT;
    int s[SCB_EPT], d[SCB_EPT];
#pragma unroll
    for (int j = 0; j < SCB_EPT; ++j) {
        int e = base + j * 256 + tid;
        if (e < E) {
            s[j] = ldidx(ei, e, e64, E, 0);
            d[j] = ldidx(ei, e, e64, E, 1);
            atomicAdd(&lcnt[d[j] >> 8], 1);
        } else d[j] = -1;
    }
    __syncthreads();
    for (int i = tid; i < NB; i += 256) {
        int c = lcnt[i];
        lbase[i] = c ? atomicAdd(&bcur[i], c) : 0;
    }
    __syncthreads();
#pragma unroll
    for (int j = 0; j < SCB_EPT; ++j) {
        if (d[j] >= 0) {
            int b = d[j] >> 8;
            int r = atomicAdd(&lrank[b], 1);
            recs[lbase[b] + r] = ((unsigned)s[j] << 8) | (unsigned)(d[j] & 255);
        }
    }
}

// one block per bucket: node counts + scan -> rowptr, dinv; then scatter srcs
// into the bucket's contiguous range (L2-local full-line writes)
__global__ __launch_bounds__(256) void k_bucket_csr(const unsigned* __restrict__ recs,
                                                    const int* __restrict__ bbase,
                                                    int* __restrict__ rowptr,
                                                    float* __restrict__ dinv,
                                                    int* __restrict__ srcs,
                                                    int n, int E) {
    __shared__ int lcnt[256];
    __shared__ int lcur[256];
    int b = blockIdx.x, tid = threadIdx.x;
    int e0 = bbase[b], e1 = bbase[b + 1];
    lcnt[tid] = 0;
    __syncthreads();
    for (int i = e0 + tid; i < e1; i += 256)
        atomicAdd(&lcnt[recs[i] & 255u], 1);
    __syncthreads();
    int c = lcnt[tid];
    lcur[tid] = c;
    __syncthreads();
    for (int off = 1; off < 256; off <<= 1) {
        int t = (tid >= off) ? lcur[tid - off] : 0;
        __syncthreads();
        lcur[tid] += t;
        __syncthreads();
    }
    int rp = bbase[b] + lcur[tid] - c;   // exclusive
    int node = (b << 8) + tid;
    if (node < n) {
        rowptr[node] = rp;
        dinv[node] = rsqrtf((float)(c + 1));
    }
    lcur[tid] = rp;
    __syncthreads();
    for (int i = e0 + tid; i < e1; i += 256) {
        unsigned r = recs[i];
        int pos = atomicAdd(&lcur[r & 255u], 1);
        srcs[pos] = (int)(r >> 8);
    }
    if (b == 0 && tid == 0) rowptr[n] = E;
}

// ---------------- MFMA dense transform (both modes): A = (X @ W)*rowscale ----------------
// f32 data path uses split-bf16 (hi+lo) with 3 MFMAs per product tile:
//   x*w ~= xh*wh + xh*wl + xl*wh      (drops xl*wl, ~2^-16 relative)
// bf16 data degenerates to lo==0. 4 waves/block, 64 rows x 64 cols per block.
template <int K, bool XALWAYSF32>
__global__ __launch_bounds__(256) void k_gconv_mfma(const void* __restrict__ Xa,
                                                    const void* __restrict__ Xb,
                                                    const void* __restrict__ W,
                                                    const float* __restrict__ flags,
                                                    const float* __restrict__ rowscale,
                                                    float* __restrict__ out, int n) {
    constexpr int KP = K + 8;
    __shared__ __align__(16) unsigned short wh[64 * KP];
    __shared__ __align__(16) unsigned short wlo[64 * KP];
    bool f32m = flags[0] > 0.5f;
    const void* X = f32m ? Xa : Xb;
    bool xf32 = XALWAYSF32 || f32m;
    int tid = threadIdx.x;

    // stage W^T split into hi/lo bf16 bits
    if (f32m) {
        for (int i = tid * 4; i < K * 64; i += 1024) {
            int k = i >> 6, c = i & 63;
            float4 v = *(const float4*)((const float*)W + i);
            float vv[4] = {v.x, v.y, v.z, v.w};
#pragma unroll
            for (int q = 0; q < 4; ++q) {
                unsigned short h = f2bf(vv[q]);
                unsigned short l = f2bf(vv[q] - bf2f(h));
                wh [(c + q) * KP + k] = h;
                wlo[(c + q) * KP + k] = l;
            }
        }
    } else {
        for (int i = tid; i < K * 64; i += 256) {
            int k = i >> 6, c = i & 63;
            wh [c * KP + k] = ((const unsigned short*)W)[i];
            wlo[c * KP + k] = 0;
        }
    }
    __syncthreads();

    int lane = tid & 63, wv = tid >> 6;
    int r0 = blockIdx.x * 64 + wv * 16;
    int mrow = lane & 15, kgrp = lane >> 4;
    int row = r0 + mrow;
    bool rok = (row < n);

    f32x4 acc[4];
#pragma unroll
    for (int ct = 0; ct < 4; ++ct) acc[ct] = (f32x4){0.0f, 0.0f, 0.0f, 0.0f};

    const float*          xrf = (const float*)X          + (size_t)(rok ? row : 0) * K;
    const unsigned short* xrb = (const unsigned short*)X + (size_t)(rok ? row : 0) * K;

#pragma unroll
    for (int ks = 0; ks < K / 32; ++ks) {
        int kb = ks * 32 + kgrp * 8;
        bf16x8 ahi = {0, 0, 0, 0, 0, 0, 0, 0};
        bf16x8 alo = {0, 0, 0, 0, 0, 0, 0, 0};
        if (rok) {
            if (xf32) {
                float4 v0 = *(const float4*)(xrf + kb);
                float4 v1 = *(const float4*)(xrf + kb + 4);
                float fv[8] = {v0.x, v0.y, v0.z, v0.w, v1.x, v1.y, v1.z, v1.w};
#pragma unroll
                for (int j = 0; j < 8; ++j) {
                    unsigned short h = f2bf(fv[j]);
                    ahi[j] = (short)h;
                    alo[j] = (short)f2bf(fv[j] - bf2f(h));
                }
            } else {
                ahi = *(const bf16x8*)(xrb + kb);   // alo stays 0
            }
        }
#pragma unroll
        for (int ct = 0; ct < 4; ++ct) {
            int c = ct * 16 + mrow;
            bf16x8 bhi = *(const bf16x8*)&wh [c * KP + kb];
            bf16x8 blo = *(const bf16x8*)&wlo[c * KP + kb];
            acc[ct] = __builtin_amdgcn_mfma_f32_16x16x32_bf16(ahi, bhi, acc[ct], 0, 0, 0);
            acc[ct] = __builtin_amdgcn_mfma_f32_16x16x32_bf16(ahi, blo, acc[ct], 0, 0, 0);
            acc[ct] = __builtin_amdgcn_mfma_f32_16x16x32_bf16(alo, bhi, acc[ct], 0, 0, 0);
        }
    }

    // C/D: col = ct*16 + (lane&15), row(within tile) = kgrp*4 + reg
    float sc[4];
    int obase = r0 + kgrp * 4;
#pragma unroll
    for (int r = 0; r < 4; ++r)
        sc[r] = (obase + r < n) ? rowscale[obase + r] : 0.0f;
#pragma unroll
    for (int ct = 0; ct < 4; ++ct) {
#pragma unroll
        for (int r = 0; r < 4; ++r) {
            int orow = obase + r;
            if (orow < n)
                out[(size_t)orow * 64 + ct * 16 + mrow] = acc[ct][r] * sc[r];
        }
    }
}

// ---------------- fused aggregation: 1 node per 16-lane group (4/wave) ----------------
// t = f32 A_scaled (rows pre-multiplied by dinv[src]); each lane owns 4 fixed
// columns -> in-register accumulation, NO cross-lane reduction. 4 independent
// gather chains per wave, 4-deep unrolled -> up to 16 rows (256B each) in flight.
template <int EP>
__global__ __launch_bounds__(256) void k_agg(const float* __restrict__ t,
                                             const float* __restrict__ dinv,
                                             const int* __restrict__ rowptr,
                                             const int* __restrict__ srcs,
                                             const void* __restrict__ bias,
                                             const float* __restrict__ flags,
                                             void* __restrict__ d_out, size_t emb_base,
                                             float* __restrict__ B_ws, int n) {
    bool f32m = flags[0] > 0.5f;
    int wvid = (blockIdx.x * 256 + threadIdx.x) >> 6;   // global wave id
    int lane = threadIdx.x & 63;
    int grp = lane >> 4;      // group = node slot
    int sub = lane & 15;      // column group: cols sub*4 .. sub*4+3
    int v = wvid * 4 + grp;
    if (v >= n) return;

    float dv = dinv[v];
    int e0 = rowptr[v], e1 = rowptr[v + 1];
    int deg = e1 - e0;

    // self row (item outside the neighbor loop)
    float4 acc = *(const float4*)(t + ((size_t)v << 6) + sub * 4);

    for (int base = 0; base < deg; base += 16) {
        int idx = base + sub;
        int sid = (idx < deg) ? srcs[e0 + idx] : -1;   // 16 ids per group, coalesced
        int cnt = deg - base; if (cnt > 16) cnt = 16;
        for (int j = 0; j < cnt; j += 4) {
            int gb = grp * 16 + j;
            int s0 = __shfl(sid, gb + 0, 64);
            int s1 = __shfl(sid, gb + 1, 64);
            int s2 = __shfl(sid, gb + 2, 64);
            int s3 = __shfl(sid, gb + 3, 64);
            float4 r0 = {0, 0, 0, 0}, r1 = {0, 0, 0, 0}, r2 = {0, 0, 0, 0}, r3 = {0, 0, 0, 0};
            if (s0 >= 0) r0 = *(const float4*)(t + ((size_t)s0 << 6) + sub * 4);
            if (s1 >= 0) r1 = *(const float4*)(t + ((size_t)s1 << 6) + sub * 4);
            if (s2 >= 0) r2 = *(const float4*)(t + ((size_t)s2 << 6) + sub * 4);
            if (s3 >= 0) r3 = *(const float4*)(t + ((size_t)s3 << 6) + sub * 4);
            acc.x += (r0.x + r1.x) + (r2.x + r3.x);
            acc.y += (r0.y + r1.y) + (r2.y + r3.y);
            acc.z += (r0.z + r1.z) + (r2.z + r3.z);
            acc.w += (r0.w + r1.w) + (r2.w + r3.w);
        }
    }

    // bias for this lane's column group
    float4 bias4;
    if (f32m) {
        bias4 = ((const float4*)bias)[sub];
    } else {
        const bf16* bp = (const bf16*)bias + sub * 4;
        bias4.x = __bfloat162float(bp[0]); bias4.y = __bfloat162float(bp[1]);
        bias4.z = __bfloat162float(bp[2]); bias4.w = __bfloat162float(bp[3]);
    }

    float4 o;
    o.x = acc.x * dv + bias4.x;
    o.y = acc.y * dv + bias4.y;
    o.z = acc.z * dv + bias4.z;
    o.w = acc.w * dv + bias4.w;
    if (EP == 0) {
        o.x = fmaxf(o.x, 0.0f); o.y = fmaxf(o.y, 0.0f);
        o.z = fmaxf(o.z, 0.0f); o.w = fmaxf(o.w, 0.0f);
    }
    size_t ob = ((size_t)v << 6) + sub * 4;
    if (f32m) {
        *(float4*)((float*)d_out + emb_base + ob) = o;   // 16 lanes -> 256B row
    } else {
        *(float4*)&B_ws[ob] = o;
        if (EP == 1) {
            __hip_bfloat162 h0, h1;
            h0.x = __float2bfloat16(o.x); h0.y = __float2bfloat16(o.y);
            h1.x = __float2bfloat16(o.z); h1.y = __float2bfloat16(o.w);
            __hip_bfloat162* p = (__hip_bfloat162*)((bf16*)d_out + emb_base + ob);
            p[0] = h0; p[1] = h1;
        }
    }
}

// ---------------- classifier: one thread per node, logits in registers ----------------

__device__ __forceinline__ void store_row40(void* out, size_t base, const float* a, bool f32m) {
    if (f32m) {
        float4* p = (float4*)((float*)out + base);
#pragma unroll
        for (int q = 0; q < 10; ++q) {
            float4 st = {a[q * 4 + 0], a[q * 4 + 1], a[q * 4 + 2], a[q * 4 + 3]};
            p[q] = st;
        }
    } else {
        __hip_bfloat162* p = (__hip_bfloat162*)((bf16*)out + base);
#pragma unroll
        for (int i = 0; i < 20; ++i) {
            __hip_bfloat162 h;
            h.x = __float2bfloat16(a[2 * i]);
            h.y = __float2bfloat16(a[2 * i + 1]);
            p[i] = h;
        }
    }
}

__global__ __launch_bounds__(256) void k_classifier(const float* __restrict__ flags,
                                                    const void* __restrict__ Wc,
                                                    const void* __restrict__ bc,
                                                    void* __restrict__ out,
                                                    size_t emb_base, size_t soft_base,
                                                    size_t hard_base,
                                                    const float* __restrict__ B_ws,
                                                    int n) {
    __shared__ __align__(16) float wcs[64 * 40];
    __shared__ __align__(16) float bcs[40];
    bool f32m = flags[0] > 0.5f;
    const float* emb = f32m ? ((const float*)out + emb_base) : B_ws;
    int tid = threadIdx.x;

    if (f32m) {
        for (int i = tid * 4; i < 64 * 40; i += 1024)
            *(float4*)&wcs[i] = *(const float4*)((const float*)Wc + i);
    } else {
        for (int i = tid; i < 64 * 40; i += 256)
            wcs[i] = __bfloat162float(((const bf16*)Wc)[i]);
    }
    if (tid < 40) bcs[tid] = loadf(bc, tid, f32m);
    __syncthreads();

    int node = blockIdx.x * 256 + tid;
    if (node >= n) return;

    float acc[40];
#pragma unroll
    for (int q = 0; q < 10; ++q) {
        float4 b4 = *(const float4*)&bcs[q * 4];
        acc[q * 4 + 0] = b4.x; acc[q * 4 + 1] = b4.y;
        acc[q * 4 + 2] = b4.z; acc[q * 4 + 3] = b4.w;
    }

    const float4* erow = (const float4*)(emb + (size_t)node * 64);
#pragma unroll 2
    for (int j = 0; j < 16; ++j) {
        float4 e4 = erow[j];
        float ev[4] = {e4.x, e4.y, e4.z, e4.w};
#pragma unroll
        for (int kk = 0; kk < 4; ++kk) {
            float e = ev[kk];
            const float4* wr = (const float4*)&wcs[(j * 4 + kk) * 40];
#pragma unroll
            for (int q = 0; q < 10; ++q) {
                float4 w = wr[q];                       // wave-uniform LDS broadcast
                acc[q * 4 + 0] = fmaf(e, w.x, acc[q * 4 + 0]);
                acc[q * 4 + 1] = fmaf(e, w.y, acc[q * 4 + 1]);
                acc[q * 4 + 2] = fmaf(e, w.z, acc[q * 4 + 2]);
                acc[q * 4 + 3] = fmaf(e, w.w, acc[q * 4 + 3]);
            }
        }
    }

    // logits
    store_row40(out, (size_t)node * 40, acc, f32m);

    // max (tree)
    float m0 = acc[0], m1 = acc[1], m2 = acc[2], m3 = acc[3];
#pragma unroll
    for (int q = 1; q < 10; ++q) {
        m0 = fmaxf(m0, acc[q * 4 + 0]); m1 = fmaxf(m1, acc[q * 4 + 1]);
        m2 = fmaxf(m2, acc[q * 4 + 2]); m3 = fmaxf(m3, acc[q * 4 + 3]);
    }
    float m = fmaxf(fmaxf(m0, m1), fmaxf(m2, m3));

    // argmax: first index equal to max (matches jnp.argmax first-occurrence)
    int bi = 63;
#pragma unroll
    for (int c = 0; c < 40; ++c)
        if (acc[c] == m && c < bi) bi = c;

    // exp + sum
    float s = 0.0f;
#pragma unroll
    for (int c = 0; c < 40; ++c) {
        float e = expf(acc[c] - m);
        acc[c] = e;
        s += e;
    }
    float rs = 1.0f / s;
#pragma unroll
    for (int c = 0; c < 40; ++c) acc[c] *= rs;

    store_row40(out, soft_base + (size_t)node * 40, acc, f32m);
    storef(out, hard_base + node, (float)bi, f32m);
}

extern "C" void kernel_launch(void* const* d_in, const int* in_sizes, int n_in,
                              void* d_out, int out_size, void* d_ws, size_t ws_size,
                              hipStream_t stream) {
    const void* x  = d_in[0];
    const int*  ei = (const int*)d_in[1];
    const void* W1 = d_in[2];
    const void* b1 = d_in[3];
    const void* W2 = d_in[4];
    const void* b2 = d_in[5];
    const void* Wc = d_in[6];
    const void* bc = d_in[7];

    const int n = in_sizes[0] / 128;   // 100000
    const int E = in_sizes[1] / 2;     // 1200000
    const int NB = (n + 255) / 256;    // 391 buckets (<= 512)

    float* ws    = (float*)d_ws;
    const size_t npad = (((size_t)n + 1023) / 1024) * 1024;
    const size_t Epad = (((size_t)E + 255) / 256) * 256;
    float* flags  = ws;                         // 256
    int*   bcnt   = (int*)(ws + 256);           // 512
    int*   bbase  = (int*)(ws + 768);           // 768 (NB+1 used)
    int*   bcur   = (int*)(ws + 1536);          // 512
    int*   rowptr = (int*)(ws + 2048);          // npad (n+1 used)
    float* dinv   = (float*)(rowptr + npad);    // npad
    int*   srcs   = (int*)(dinv + npad);        // Epad
    float* A      = (float*)(srcs + Epad);      // n*64 f32 (scaled gemm outputs)
    float* B_ws   = A + (size_t)n * 64;         // n*64 f32 (only if !f32m)
    unsigned* recs = (unsigned*)B_ws;           // E packed records, aliases B_ws

    const size_t emb_base  = (size_t)n * 40;
    const size_t soft_base = (size_t)n * 104;
    const size_t hard_base = (size_t)n * 144;
    float* h1_f32m = (float*)d_out + emb_base;  // h1 scratch in emb region (f32m)

    const int gE  = (E + 256 * SCB_EPT - 1) / (256 * SCB_EPT);  // edge-pass blocks
    const int gG  = (n + 63) / 64;
    const int gW  = (n + 15) / 16;              // 4 nodes/wave, 4 waves/block
    const int gC  = (n + 255) / 256;

    k_detect<<<1, 64, 0, stream>>>(x, ei, flags);

    // CSR build via 2-level counting sort (packed 4B records)
    k_zero_small<<<2, 256, 0, stream>>>(bcnt, 512);
    k_bucket_hist<<<gE, 256, 0, stream>>>(ei, flags, bcnt, E, NB);
    k_scan_buckets<<<1, 512, 0, stream>>>(bcnt, bbase, bcur, NB);
    k_bucket_scatter<<<gE, 256, 0, stream>>>(ei, flags, bcur, recs, E, NB);
    k_bucket_csr<<<NB, 256, 0, stream>>>(recs, bbase, rowptr, dinv, srcs, n, E);

    // conv1: A = (x @ W1)*dinv  — split-bf16 MFMA (f32 mode) / plain MFMA (bf16 mode)
    k_gconv_mfma<128, false><<<gG, 256, 0, stream>>>(x, x, W1, flags, dinv, A, n);
    k_agg<0><<<gW, 256, 0, stream>>>(A, dinv, rowptr, srcs, b1, flags,
                                     d_out, emb_base, B_ws, n);

    // conv2: A = (h1 @ W2)*dinv ; h1 is f32 in both modes
    k_gconv_mfma<64, true><<<gG, 256, 0, stream>>>(h1_f32m, B_ws, W2, flags, dinv, A, n);
    k_agg<1><<<gW, 256, 0, stream>>>(A, dinv, rowptr, srcs, b2, flags,
                                     d_out, emb_base, B_ws, n);

    // classifier + softmax + argmax
    k_classifier<<<gC, 256, 0, stream>>>(flags, Wc, bc, d_out,
                                         emb_base, soft_base, hard_base, B_ws, n);
}